// Round 21
// baseline (96.111 us; speedup 1.0000x reference)
//
#include <hip/hip_runtime.h>
#include <hip/hip_cooperative_groups.h>

namespace cg = cooperative_groups;

#define PRE_K 1000
#define CAP   2048      // candidate buffer per level (>= PRE_K + max bin, pow2)
#define NBIN  8192      // 13-bit key-prefix histogram bins
#define NB    1000      // boxes per level after pre-NMS topk
#define NW    16        // 64-bit words covering NB bits
#define TOT   4000      // concatenated entries per batch
#define NLVL  4
#define BATCH 8
#define HB    8         // blocks per (b,lvl) for hist/collect
#define MBM   16        // blocks per (b,lvl) for mask build (fallback)
#define SB    8         // blocks per (b,lvl) for sortemit (8*256 == CAP)
#define CGRID 256       // cooperative grid (1 block/CU)

__device__ __forceinline__ unsigned f2key(float f) {
    unsigned u = __float_as_uint(f);
    return (u & 0x80000000u) ? ~u : (u | 0x80000000u);   // monotonic ascending
}
__device__ __forceinline__ float key2f(unsigned k) {
    unsigned u = (k & 0x80000000u) ? (k & 0x7FFFFFFFu) : ~k;
    return __uint_as_float(u);
}
__device__ __forceinline__ const float* lvl_scores(
    const float* s0, const float* s1, const float* s2, const float* s3, int lvl) {
    switch (lvl) { case 0: return s0; case 1: return s1; case 2: return s2; default: return s3; }
}
__device__ __forceinline__ const float* lvl_boxes(
    const float* b0, const float* b1, const float* b2, const float* b3, int lvl) {
    switch (lvl) { case 0: return b0; case 1: return b1; case 2: return b2; default: return b3; }
}
__device__ __forceinline__ int lvl_n(int lvl) {
    const int sizes[4] = {196608, 49152, 12288, 3072};
    return sizes[lvl];
}
__device__ __forceinline__ float bcast_f(float v, int i) {
    return __int_as_float(__builtin_amdgcn_readlane(__float_as_int(v), i));
}

// ===========================================================================
// COOPERATIVE single-launch kernel: all R16 phases at their natural widths,
// kernel boundaries replaced by grid.sync(). 256 blocks x 512 threads,
// 152 KB LDS union -> exactly 1 block/CU (cooperative co-residency).
// ===========================================================================
__global__ __launch_bounds__(512) void roi_coop_kernel(
    const float* __restrict__ boxes0, const float* __restrict__ scores0,
    const float* __restrict__ boxes1, const float* __restrict__ scores1,
    const float* __restrict__ boxes2, const float* __restrict__ scores2,
    const float* __restrict__ boxes3, const float* __restrict__ scores3,
    float* __restrict__ ws_scores, float* __restrict__ ws_boxes,
    unsigned long long* __restrict__ ws_mask,
    unsigned long long* __restrict__ ws_nz,
    unsigned long long* __restrict__ cand,
    unsigned* __restrict__ ghist, unsigned* __restrict__ counters,
    unsigned* __restrict__ thresh, float* __restrict__ out)
{
    cg::grid_group grid = cg::this_grid();
    const int gb   = blockIdx.x;     // 0..255
    const int tid  = threadIdx.x;    // 0..511
    const int lane = tid & 63;

    __shared__ __align__(16) unsigned char U[152000];   // phase-overlaid union
    __shared__ unsigned csum[256];
    __shared__ unsigned long long nzlds[NW], keepw[NW];
    __shared__ int wprefix[NW];
    __shared__ int s_chunk, sL;
    __shared__ unsigned s_before, ccnt, cbase;

    // ---------------- P0: zero ghist + nz ----------------
    for (int i = gb * 512 + tid; i < 32 * NBIN; i += CGRID * 512) ghist[i] = 0u;
    if (gb == 0 && tid < 32 * NW) ws_nz[tid] = 0ull;
    __threadfence();
    grid.sync();

    // ---------------- P1: histogram (R16 body) ----------------
    {
        const int blk = gb / HB, hb = gb % HB;
        const int b = blk >> 2, lvl = blk & 3;
        const int n = lvl_n(lvl);
        const float* sc = lvl_scores(scores0, scores1, scores2, scores3, lvl) + (size_t)b * n;
        unsigned* lhist = (unsigned*)U;             // [2][NBIN] = 64 KB
        const int rep = (tid >> 6) & 1;
        for (int i = tid; i < 2 * NBIN; i += 512) lhist[i] = 0u;
        __syncthreads();
        const float4* sc4 = (const float4*)sc;
        const int n4 = n >> 2;
        for (int i = hb * 512 + tid; i < n4; i += HB * 512) {
            float4 v = sc4[i];
            atomicAdd(&lhist[rep * NBIN + (f2key(v.x) >> 19)], 1u);
            atomicAdd(&lhist[rep * NBIN + (f2key(v.y) >> 19)], 1u);
            atomicAdd(&lhist[rep * NBIN + (f2key(v.z) >> 19)], 1u);
            atomicAdd(&lhist[rep * NBIN + (f2key(v.w) >> 19)], 1u);
        }
        __syncthreads();
        unsigned* gh = ghist + (size_t)blk * NBIN;
        for (int i = tid; i < NBIN; i += 512) {
            unsigned v = lhist[i] + lhist[NBIN + i];
            if (v) atomicAdd(&gh[i], v);
        }
    }
    __threadfence();
    grid.sync();

    // ---------------- P2: threshold select (R16 body; blocks 0..31) -------
    if (gb < 32) {
        const unsigned* gh = ghist + (size_t)gb * NBIN;
        if (tid < 256) {
            unsigned s = 0;
            #pragma unroll 8
            for (int k = 0; k < 32; ++k) s += gh[tid * 32 + k];
            csum[tid] = s;
        }
        __syncthreads();
        if (tid < 256) {
            unsigned suf = 0;
            for (int c = tid + 1; c < 256; ++c) suf += csum[c];
            if (suf < PRE_K && suf + csum[tid] >= PRE_K) { s_chunk = tid; s_before = suf; }
        }
        __syncthreads();
        if (tid == 0) {
            int C = s_chunk;
            unsigned acc = s_before;
            int T = C * 32;
            for (int bin = C * 32 + 31; bin >= C * 32; --bin) {
                acc += gh[bin];
                if (acc >= PRE_K) { T = bin; break; }
            }
            thresh[gb]   = (unsigned)T;
            counters[gb] = 0u;
        }
    }
    __threadfence();
    grid.sync();

    // ---------------- P3: collect (R16 body) ----------------
    {
        const int blk = gb / HB, hb = gb % HB;
        const int b = blk >> 2, lvl = blk & 3;
        const int n = lvl_n(lvl);
        const float* sc = lvl_scores(scores0, scores1, scores2, scores3, lvl) + (size_t)b * n;
        const unsigned T = thresh[blk];
        unsigned long long* candp = cand + (size_t)blk * CAP;
        unsigned long long* cbuf = (unsigned long long*)U;   // [CAP] = 16 KB
        if (tid == 0) ccnt = 0;
        __syncthreads();
        for (int i = hb * 512 + tid; i < n; i += HB * 512) {
            unsigned key = f2key(sc[i]);
            bool pred = (key >> 19) >= T;
            unsigned long long act = __ballot(pred);
            if (act) {
                int leader = __ffsll((long long)act) - 1;
                unsigned base = 0;
                if (lane == leader) base = atomicAdd(&ccnt, (unsigned)__popcll(act));
                base = __shfl(base, leader, 64);
                if (pred) {
                    unsigned pos = base + (unsigned)__popcll(act & ((1ull << lane) - 1ull));
                    if (pos < CAP)
                        cbuf[pos] = ((unsigned long long)key << 32) | (unsigned)(~i);
                }
            }
        }
        __syncthreads();
        unsigned cnt = ccnt; if (cnt > CAP) cnt = CAP;
        if (tid == 0) cbase = atomicAdd(&counters[blk], cnt);
        __syncthreads();
        const unsigned gbase = cbase;
        for (unsigned i = tid; i < cnt; i += 512) {
            unsigned p = gbase + i;
            if (p < CAP) candp[p] = cbuf[i];
        }
    }
    __threadfence();
    grid.sync();

    // ---------------- P4: rank-by-count sortemit (R16 body, 512 thr) ------
    {
        const int blk = gb / SB, hb = gb % SB;
        const int b = blk >> 2, lvl = blk & 3;
        const int n = lvl_n(lvl);
        const float* bx = lvl_boxes(boxes0, boxes1, boxes2, boxes3, lvl) + (size_t)b * n * 4;
        const unsigned long long* candp = cand + (size_t)blk * CAP;
        unsigned long long* arr = (unsigned long long*)U;    // [CAP]
        int cnt = (int)counters[blk]; if (cnt > CAP) cnt = CAP;
        for (int i = tid; i < CAP; i += 512)
            arr[i] = (i < cnt) ? candp[i] : 0ull;
        __syncthreads();
        if (tid < 256) {                                     // waves 0..3
            const int i = hb * 256 + tid;
            const unsigned long long ci = (i < cnt) ? arr[i] : 0ull;
            int rank = 0;
            const int nch = (cnt + 63) >> 6;
            for (int c = 0; c < nch; ++c) {
                unsigned long long x = arr[c * 64 + lane];
                unsigned xlo = (unsigned)x, xhi = (unsigned)(x >> 32);
                #pragma unroll
                for (int k = 0; k < 64; ++k) {
                    unsigned long long xk =
                        ((unsigned long long)(unsigned)__builtin_amdgcn_readlane((int)xhi, k) << 32) |
                        (unsigned)__builtin_amdgcn_readlane((int)xlo, k);
                    rank += (xk > ci);
                }
            }
            if (i < cnt && rank < PRE_K) {
                unsigned key = (unsigned)(ci >> 32);
                int idx = (int)(~(unsigned)ci);
                ws_scores[(size_t)blk * PRE_K + rank] = key2f(key);
                const float4 bb = ((const float4*)bx)[idx];
                float* dst = ws_boxes + ((size_t)blk * PRE_K + rank) * 4;
                dst[0] = bb.x; dst[1] = bb.y; dst[2] = bb.z; dst[3] = bb.w;
            }
        }
        __syncthreads();
    }
    __threadfence();
    grid.sync();

    // ---------------- P5: mask build (R16 body; 8 blocks x 8 waves/level) -
    {
        const int blk = gb >> 3, mb = gb & 7;
        const int wv8 = tid >> 6;                            // 0..7
        float4* sbox = (float4*)U;                           // [1024] = 16 KB
        const float4* bxp = (const float4*)(ws_boxes + (size_t)blk * NB * 4);
        for (int i = tid; i < 1024; i += 512)
            sbox[i] = (i < NB) ? bxp[i] : make_float4(0.f, 0.f, 0.f, 0.f);
        __syncthreads();
        unsigned long long* maskp = ws_mask + (size_t)blk * NB * NW;
        unsigned long long* nzp   = ws_nz + (size_t)blk * NW;
        const double CSUM = (double)__uint_as_float(0x3F333333u)
                          + (double)__uint_as_float(0x3F333334u);
        for (int t = mb * 8 + wv8; t < 136; t += 64) {       // same 64 waves/level as R16
            int w = 0, acc = 0;
            while (acc + w + 1 <= t) { acc += w + 1; ++w; }
            const int rb = t - acc;
            const int rbase = rb * 64;
            const float4 rbx = sbox[rbase + lane];
            const float   ra = (rbx.z - rbx.x) * (rbx.w - rbx.y);
            const float4 cbx = sbox[w * 64 + lane];
            const float   ca = (cbx.z - cbx.x) * (cbx.w - cbx.y);
            unsigned long long myw = 0ull;
            #pragma unroll
            for (int jj = 0; jj < 64; ++jj) {
                const float cy1 = bcast_f(cbx.x, jj);
                const float cx1 = bcast_f(cbx.y, jj);
                const float cy2 = bcast_f(cbx.z, jj);
                const float cx2 = bcast_f(cbx.w, jj);
                const float caj = bcast_f(ca, jj);
                float iy1 = fmaxf(rbx.x, cy1);
                float ix1 = fmaxf(rbx.y, cx1);
                float iy2 = fminf(rbx.z, cy2);
                float ix2 = fminf(rbx.w, cx2);
                float ih = fmaxf(iy2 - iy1, 0.0f);
                float iw = fmaxf(ix2 - ix1, 0.0f);
                float inter = ih * iw;
                float uni = ra + caj - inter;
                bool pred = (uni > 0.0f) &&
                            (2.0 * (double)inter >= CSUM * (double)uni);
                myw |= ((unsigned long long)pred) << jj;
            }
            if (w == rb)
                myw &= ~((2ull << lane) - 1ull);
            if (rbase + lane < NB)
                maskp[(size_t)(rbase + lane) * NW + w] = myw;
            unsigned long long nzb = __ballot(myw != 0ull);
            if (lane == 0 && nzb) atomicOr(&nzp[rb], nzb);
        }
        __syncthreads();
    }
    __threadfence();
    grid.sync();

    // ---------------- P6: sparse greedy (R16 body, 512 thr; blocks 0..31) -
    if (gb < 32) {
        const int blk = gb;
        float* scp = ws_scores + (size_t)blk * NB;
        float* bxp = ws_boxes  + (size_t)blk * NB * 4;
        const unsigned long long* mrows = ws_mask + (size_t)blk * NB * NW;
        unsigned long long* Mrow = (unsigned long long*)U;        // 128000 B
        float4* sbox = (float4*)(U + 128000);                     // 16000 B
        float*  ssc  = (float*)(U + 144000);                      //  4000 B
        int*    slist = (int*)(U + 148000);                       //  4000 B

        if (tid < NW) nzlds[tid] = ws_nz[(size_t)blk * NW + tid];
        for (int i = tid; i < NB; i += 512) {
            sbox[i] = ((const float4*)bxp)[i];
            ssc[i]  = scp[i];
        }
        // initial keep bits: 8 waves x 2 words
        #pragma unroll
        for (int r = 0; r < 2; ++r) {
            const int w = (tid >> 6) * 2 + r;
            const int j = w * 64 + lane;
            bool pred = (j < NB) && (scp[j] > 0.0f);
            unsigned long long bal = __ballot(pred);
            if (lane == 0) keepw[w] = bal;
        }
        __syncthreads();

        if (tid == 0) {
            int L = 0;
            for (int c = 0; c < NW; ++c) {
                unsigned long long p = nzlds[c];
                while (p) {
                    int i = __ffsll((long long)p) - 1;
                    slist[L++] = c * 64 + i;
                    p &= p - 1;
                }
            }
            sL = L;
        }
        __syncthreads();
        const int L = sL;

        for (int idx = tid; idx < L * NW; idx += 512) {
            int r = slist[idx >> 4];
            Mrow[idx] = mrows[(size_t)r * NW + (idx & 15)];
        }
        __syncthreads();

        if (tid < 64) {
            unsigned long long kp = (lane < NW) ? keepw[lane] : 0ull;
            unsigned long long mnext = (L > 0 && lane < NW) ? Mrow[lane] : 0ull;
            int rnext = (L > 0) ? slist[0] : 0;
            for (int k = 0; k < L; ++k) {
                unsigned long long m = mnext;
                const int r = rnext;
                if (k + 1 < L) {
                    rnext = slist[k + 1];
                    mnext = (lane < NW) ? Mrow[(size_t)(k + 1) * NW + lane] : 0ull;
                }
                const int c = r >> 6;
                unsigned klo = (unsigned)__builtin_amdgcn_readlane((int)(unsigned)kp, c);
                unsigned khi = (unsigned)__builtin_amdgcn_readlane((int)(unsigned)(kp >> 32), c);
                unsigned long long kw = ((unsigned long long)khi << 32) | klo;
                if ((kw >> (r & 63)) & 1ull) {
                    unsigned long long mm = (lane >= c) ? m : 0ull;
                    kp &= ~mm;
                }
            }
            if (lane < NW) keepw[lane] = kp;
        }
        __syncthreads();
        if (tid == 0) {
            int acc = 0;
            for (int w = 0; w < NW; ++w) { wprefix[w] = acc; acc += __popcll(keepw[w]); }
        }
        __syncthreads();

        for (int i = tid; i < NB; i += 512) scp[i] = 0.0f;
        for (int i = tid; i < NB * 4; i += 512) bxp[i] = 0.0f;
        __syncthreads();
        for (int i = tid; i < NB; i += 512) {
            const int w = i >> 6;
            const unsigned long long kw = keepw[w];
            if ((kw >> (i & 63)) & 1ull) {
                int rank = wprefix[w] + __popcll(kw & ((1ull << (i & 63)) - 1ull));
                scp[rank] = ssc[i];
                float4 bb = sbox[i];
                float* dst = bxp + (size_t)rank * 4;
                dst[0] = bb.x; dst[1] = bb.y; dst[2] = bb.z; dst[3] = bb.w;
            }
        }
    }
    __threadfence();
    grid.sync();

    // ---------------- P7: per-(b,lvl) merge-rank (R16 body; blocks 0..31) -
    if (gb < 32) {
        const int b = gb >> 2, lvl = gb & 3;
        unsigned long long (*lists)[PRE_K] = (unsigned long long (*)[PRE_K])U;  // 32 KB
        for (int i = tid; i < TOT; i += 512) {
            unsigned u = f2key(ws_scores[(size_t)b * TOT + i]);
            lists[i / PRE_K][i % PRE_K] =
                ((unsigned long long)u << 32) | (unsigned)(~i);
        }
        __syncthreads();
        float* out_rois   = out;            // (8,1000,4)
        float* out_scores = out + 32000;    // (8,1000)
        for (int r = tid; r < PRE_K; r += 512) {
            const unsigned long long c = lists[lvl][r];
            int rank = r;
            #pragma unroll
            for (int l = 0; l < NLVL; ++l) {
                if (l == lvl) continue;
                int lo = 0, hi = PRE_K;
                while (lo < hi) {
                    int mid = (lo + hi) >> 1;
                    if (lists[l][mid] > c) lo = mid + 1; else hi = mid;
                }
                rank += lo;
            }
            if (rank < PRE_K) {
                out_scores[(size_t)b * PRE_K + rank] = key2f((unsigned)(c >> 32));
                const int pos = lvl * PRE_K + r;
                const float4 bb = ((const float4*)ws_boxes)[(size_t)b * TOT + pos];
                float* dst = out_rois + ((size_t)b * PRE_K + rank) * 4;
                dst[0] = bb.x; dst[1] = bb.y; dst[2] = bb.z; dst[3] = bb.w;
            }
        }
    }
}

// ===========================================================================
// Fallback: the exact R16/R20 8-kernel chain (verified 96 us, absmax 0).
// ===========================================================================
__global__ __launch_bounds__(512) void init_kernel(
    unsigned* __restrict__ ghist, unsigned long long* __restrict__ ws_nz) {
    const int stride = gridDim.x * 512;
    for (int i = blockIdx.x * 512 + threadIdx.x; i < 32 * NBIN; i += stride)
        ghist[i] = 0u;
    for (int i = blockIdx.x * 512 + threadIdx.x; i < 32 * NW; i += stride)
        ws_nz[i] = 0ull;
}

__global__ __launch_bounds__(512) void hist_kernel(
    const float* __restrict__ scores0, const float* __restrict__ scores1,
    const float* __restrict__ scores2, const float* __restrict__ scores3,
    unsigned* __restrict__ ghist)
{
    const int blk = blockIdx.x / HB;
    const int hb  = blockIdx.x % HB;
    const int b   = blk >> 2;
    const int lvl = blk & 3;
    const int n   = lvl_n(lvl);
    const float* sc = lvl_scores(scores0, scores1, scores2, scores3, lvl) + (size_t)b * n;

    __shared__ unsigned lhist[2][NBIN];
    const int tid = threadIdx.x;
    const int rep = (tid >> 6) & 1;
    for (int i = tid; i < 2 * NBIN; i += 512) (&lhist[0][0])[i] = 0u;
    __syncthreads();

    const float4* sc4 = (const float4*)sc;
    const int n4 = n >> 2;
    for (int i = hb * 512 + tid; i < n4; i += HB * 512) {
        float4 v = sc4[i];
        atomicAdd(&lhist[rep][f2key(v.x) >> 19], 1u);
        atomicAdd(&lhist[rep][f2key(v.y) >> 19], 1u);
        atomicAdd(&lhist[rep][f2key(v.z) >> 19], 1u);
        atomicAdd(&lhist[rep][f2key(v.w) >> 19], 1u);
    }
    __syncthreads();

    unsigned* gh = ghist + (size_t)blk * NBIN;
    for (int i = tid; i < NBIN; i += 512) {
        unsigned v = lhist[0][i] + lhist[1][i];
        if (v) atomicAdd(&gh[i], v);
    }
}

__global__ __launch_bounds__(256) void select_kernel(
    const unsigned* __restrict__ ghist,
    unsigned* __restrict__ thresh,
    unsigned* __restrict__ counters)
{
    const int blk = blockIdx.x;
    const int tid = threadIdx.x;
    const unsigned* gh = ghist + (size_t)blk * NBIN;

    __shared__ unsigned csum[256];
    __shared__ int s_chunk;
    __shared__ unsigned s_before;

    unsigned s = 0;
    #pragma unroll 8
    for (int k = 0; k < 32; ++k) s += gh[tid * 32 + k];
    csum[tid] = s;
    __syncthreads();

    unsigned suf = 0;
    for (int c = tid + 1; c < 256; ++c) suf += csum[c];
    if (suf < PRE_K && suf + csum[tid] >= PRE_K) { s_chunk = tid; s_before = suf; }
    __syncthreads();

    if (tid == 0) {
        int C = s_chunk;
        unsigned acc = s_before;
        int T = C * 32;
        for (int bin = C * 32 + 31; bin >= C * 32; --bin) {
            acc += gh[bin];
            if (acc >= PRE_K) { T = bin; break; }
        }
        thresh[blk]   = (unsigned)T;
        counters[blk] = 0u;
    }
}

__global__ __launch_bounds__(512) void collect_kernel(
    const float* __restrict__ scores0, const float* __restrict__ scores1,
    const float* __restrict__ scores2, const float* __restrict__ scores3,
    const unsigned* __restrict__ thresh,
    unsigned* __restrict__ counters,
    unsigned long long* __restrict__ cand)
{
    const int blk = blockIdx.x / HB;
    const int hb  = blockIdx.x % HB;
    const int b   = blk >> 2;
    const int lvl = blk & 3;
    const int n   = lvl_n(lvl);
    const float* sc = lvl_scores(scores0, scores1, scores2, scores3, lvl) + (size_t)b * n;
    const unsigned T = thresh[blk];
    unsigned long long* candp = cand + (size_t)blk * CAP;

    __shared__ unsigned long long cbuf[CAP];
    __shared__ unsigned ccnt, cbase;

    const int tid  = threadIdx.x;
    const int lane = tid & 63;
    if (tid == 0) ccnt = 0;
    __syncthreads();

    for (int i = hb * 512 + tid; i < n; i += HB * 512) {
        unsigned key = f2key(sc[i]);
        bool pred = (key >> 19) >= T;
        unsigned long long act = __ballot(pred);
        if (act) {
            int leader = __ffsll((long long)act) - 1;
            unsigned base = 0;
            if (lane == leader) base = atomicAdd(&ccnt, (unsigned)__popcll(act));
            base = __shfl(base, leader, 64);
            if (pred) {
                unsigned pos = base + (unsigned)__popcll(act & ((1ull << lane) - 1ull));
                if (pos < CAP)
                    cbuf[pos] = ((unsigned long long)key << 32) | (unsigned)(~i);
            }
        }
    }
    __syncthreads();
    unsigned cnt = ccnt; if (cnt > CAP) cnt = CAP;
    if (tid == 0) cbase = atomicAdd(&counters[blk], cnt);
    __syncthreads();
    const unsigned gbv = cbase;
    for (unsigned i = tid; i < cnt; i += 512) {
        unsigned p = gbv + i;
        if (p < CAP) candp[p] = cbuf[i];
    }
}

__global__ __launch_bounds__(256) void sortemit_kernel(
    const float* __restrict__ boxes0, const float* __restrict__ boxes1,
    const float* __restrict__ boxes2, const float* __restrict__ boxes3,
    const unsigned* __restrict__ counters,
    const unsigned long long* __restrict__ cand,
    float* __restrict__ ws_scores,
    float* __restrict__ ws_boxes)
{
    const int blk = blockIdx.x / SB;
    const int hb  = blockIdx.x % SB;
    const int b   = blk >> 2;
    const int lvl = blk & 3;
    const int n   = lvl_n(lvl);
    const float* bx = lvl_boxes(boxes0, boxes1, boxes2, boxes3, lvl) + (size_t)b * n * 4;
    const unsigned long long* candp = cand + (size_t)blk * CAP;

    __shared__ unsigned long long arr[CAP];
    const int tid  = threadIdx.x;
    const int lane = tid & 63;
    int cnt = (int)counters[blk]; if (cnt > CAP) cnt = CAP;

    for (int i = tid; i < CAP; i += 256)
        arr[i] = (i < cnt) ? candp[i] : 0ull;
    __syncthreads();

    const int i = hb * 256 + tid;
    const unsigned long long ci = (i < cnt) ? arr[i] : 0ull;
    int rank = 0;
    const int nch = (cnt + 63) >> 6;
    for (int c = 0; c < nch; ++c) {
        unsigned long long x = arr[c * 64 + lane];
        unsigned xlo = (unsigned)x, xhi = (unsigned)(x >> 32);
        #pragma unroll
        for (int k = 0; k < 64; ++k) {
            unsigned long long xk =
                ((unsigned long long)(unsigned)__builtin_amdgcn_readlane((int)xhi, k) << 32) |
                (unsigned)__builtin_amdgcn_readlane((int)xlo, k);
            rank += (xk > ci);
        }
    }
    if (i < cnt && rank < PRE_K) {
        unsigned key = (unsigned)(ci >> 32);
        int idx = (int)(~(unsigned)ci);
        ws_scores[(size_t)blk * PRE_K + rank] = key2f(key);
        const float4 bb = ((const float4*)bx)[idx];
        float* dst = ws_boxes + ((size_t)blk * PRE_K + rank) * 4;
        dst[0] = bb.x; dst[1] = bb.y; dst[2] = bb.z; dst[3] = bb.w;
    }
}

__global__ __launch_bounds__(256) void mask_kernel(
    const float* __restrict__ ws_boxes,
    unsigned long long* __restrict__ ws_mask,
    unsigned long long* __restrict__ ws_nz)
{
    const int blk  = blockIdx.x / MBM;
    const int mb   = blockIdx.x % MBM;
    const int tid  = threadIdx.x;
    const int lane = tid & 63;
    const int wv   = tid >> 6;

    __shared__ float4 sbox[1024];

    const float4* bxp = (const float4*)(ws_boxes + (size_t)blk * NB * 4);
    for (int i = tid; i < 1024; i += 256)
        sbox[i] = (i < NB) ? bxp[i] : make_float4(0.f, 0.f, 0.f, 0.f);
    __syncthreads();

    unsigned long long* maskp = ws_mask + (size_t)blk * NB * NW;
    unsigned long long* nzp   = ws_nz + (size_t)blk * NW;
    const double CSUM = (double)__uint_as_float(0x3F333333u)
                      + (double)__uint_as_float(0x3F333334u);

    for (int t = mb * 4 + wv; t < 136; t += MBM * 4) {
        int w = 0, acc = 0;
        while (acc + w + 1 <= t) { acc += w + 1; ++w; }
        const int rb = t - acc;
        const int rbase = rb * 64;

        const float4 rbx = sbox[rbase + lane];
        const float   ra = (rbx.z - rbx.x) * (rbx.w - rbx.y);
        const float4 cbx = sbox[w * 64 + lane];
        const float   ca = (cbx.z - cbx.x) * (cbx.w - cbx.y);

        unsigned long long myw = 0ull;
        #pragma unroll
        for (int jj = 0; jj < 64; ++jj) {
            const float cy1 = bcast_f(cbx.x, jj);
            const float cx1 = bcast_f(cbx.y, jj);
            const float cy2 = bcast_f(cbx.z, jj);
            const float cx2 = bcast_f(cbx.w, jj);
            const float caj = bcast_f(ca, jj);
            float iy1 = fmaxf(rbx.x, cy1);
            float ix1 = fmaxf(rbx.y, cx1);
            float iy2 = fminf(rbx.z, cy2);
            float ix2 = fminf(rbx.w, cx2);
            float ih = fmaxf(iy2 - iy1, 0.0f);
            float iw = fmaxf(ix2 - ix1, 0.0f);
            float inter = ih * iw;
            float uni = ra + caj - inter;
            bool pred = (uni > 0.0f) &&
                        (2.0 * (double)inter >= CSUM * (double)uni);
            myw |= ((unsigned long long)pred) << jj;
        }
        if (w == rb)
            myw &= ~((2ull << lane) - 1ull);
        if (rbase + lane < NB)
            maskp[(size_t)(rbase + lane) * NW + w] = myw;
        unsigned long long nzb = __ballot(myw != 0ull);
        if (lane == 0 && nzb) atomicOr(&nzp[rb], nzb);
    }
}

__global__ __launch_bounds__(1024) void greedy_kernel(
    float* __restrict__ ws_scores,
    float* __restrict__ ws_boxes,
    const unsigned long long* __restrict__ ws_mask,
    const unsigned long long* __restrict__ ws_nz)
{
    const int blk  = blockIdx.x;
    const int tid  = threadIdx.x;
    const int lane = tid & 63;
    const int wv   = tid >> 6;

    __shared__ unsigned long long Mrow[NB * NW];
    __shared__ float4 sbox[NB];
    __shared__ float  ssc[NB];
    __shared__ unsigned long long nzlds[NW];
    __shared__ unsigned long long keepw[NW];
    __shared__ int wprefix[NW];
    __shared__ int slist[NB];
    __shared__ int sL;

    float* scp = ws_scores + (size_t)blk * NB;
    float* bxp = ws_boxes  + (size_t)blk * NB * 4;
    const unsigned long long* mrows = ws_mask + (size_t)blk * NB * NW;

    if (tid < NW) nzlds[tid] = ws_nz[(size_t)blk * NW + tid];
    for (int i = tid; i < NB; i += 1024) {
        sbox[i] = ((const float4*)bxp)[i];
        ssc[i]  = scp[i];
    }
    {
        const int j = wv * 64 + lane;
        bool pred = (j < NB) && (scp[j] > 0.0f);
        unsigned long long bal = __ballot(pred);
        if (lane == 0) keepw[wv] = bal;
    }
    __syncthreads();

    if (tid == 0) {
        int L = 0;
        for (int c = 0; c < NW; ++c) {
            unsigned long long p = nzlds[c];
            while (p) {
                int i = __ffsll((long long)p) - 1;
                slist[L++] = c * 64 + i;
                p &= p - 1;
            }
        }
        sL = L;
    }
    __syncthreads();
    const int L = sL;

    for (int idx = tid; idx < L * NW; idx += 1024) {
        int r = slist[idx >> 4];
        Mrow[idx] = mrows[(size_t)r * NW + (idx & 15)];
    }
    __syncthreads();

    if (tid < 64) {
        unsigned long long kp = (lane < NW) ? keepw[lane] : 0ull;
        unsigned long long mnext = (L > 0 && lane < NW) ? Mrow[lane] : 0ull;
        int rnext = (L > 0) ? slist[0] : 0;
        for (int k = 0; k < L; ++k) {
            unsigned long long m = mnext;
            const int r = rnext;
            if (k + 1 < L) {
                rnext = slist[k + 1];
                mnext = (lane < NW) ? Mrow[(size_t)(k + 1) * NW + lane] : 0ull;
            }
            const int c = r >> 6;
            unsigned klo = (unsigned)__builtin_amdgcn_readlane((int)(unsigned)kp, c);
            unsigned khi = (unsigned)__builtin_amdgcn_readlane((int)(unsigned)(kp >> 32), c);
            unsigned long long kw = ((unsigned long long)khi << 32) | klo;
            if ((kw >> (r & 63)) & 1ull) {
                unsigned long long mm = (lane >= c) ? m : 0ull;
                kp &= ~mm;
            }
        }
        if (lane < NW) keepw[lane] = kp;
    }
    __syncthreads();
    if (tid == 0) {
        int acc = 0;
        for (int w = 0; w < NW; ++w) { wprefix[w] = acc; acc += __popcll(keepw[w]); }
    }
    __syncthreads();

    for (int i = tid; i < NB; i += 1024) scp[i] = 0.0f;
    for (int i = tid; i < NB * 4; i += 1024) bxp[i] = 0.0f;
    __syncthreads();
    for (int i = tid; i < NB; i += 1024) {
        const int w = i >> 6;
        const unsigned long long kw = keepw[w];
        if ((kw >> (i & 63)) & 1ull) {
            int rank = wprefix[w] + __popcll(kw & ((1ull << (i & 63)) - 1ull));
            scp[rank] = ssc[i];
            float4 bb = sbox[i];
            float* dst = bxp + (size_t)rank * 4;
            dst[0] = bb.x; dst[1] = bb.y; dst[2] = bb.z; dst[3] = bb.w;
        }
    }
}

__global__ __launch_bounds__(1024) void final_merge_kernel(
    const float* __restrict__ ws_scores,
    const float* __restrict__ ws_boxes,
    float* __restrict__ out)
{
    const int blk = blockIdx.x;
    const int b   = blk >> 2;
    const int lvl = blk & 3;
    const int tid = threadIdx.x;

    __shared__ unsigned long long lists[NLVL][PRE_K];

    for (int i = tid; i < TOT; i += 1024) {
        unsigned u = f2key(ws_scores[(size_t)b * TOT + i]);
        lists[i / PRE_K][i % PRE_K] =
            ((unsigned long long)u << 32) | (unsigned)(~i);
    }
    __syncthreads();

    float* out_rois   = out;
    float* out_scores = out + 32000;

    for (int r = tid; r < PRE_K; r += 1024) {
        const unsigned long long c = lists[lvl][r];
        int rank = r;
        #pragma unroll
        for (int l = 0; l < NLVL; ++l) {
            if (l == lvl) continue;
            int lo = 0, hi = PRE_K;
            while (lo < hi) {
                int mid = (lo + hi) >> 1;
                if (lists[l][mid] > c) lo = mid + 1; else hi = mid;
            }
            rank += lo;
        }
        if (rank < PRE_K) {
            out_scores[(size_t)b * PRE_K + rank] = key2f((unsigned)(c >> 32));
            const int pos = lvl * PRE_K + r;
            const float4 bb = ((const float4*)ws_boxes)[(size_t)b * TOT + pos];
            float* dst = out_rois + ((size_t)b * PRE_K + rank) * 4;
            dst[0] = bb.x; dst[1] = bb.y; dst[2] = bb.z; dst[3] = bb.w;
        }
    }
}

// ---------------------------------------------------------------------------
extern "C" void kernel_launch(void* const* d_in, const int* in_sizes, int n_in,
                              void* d_out, int out_size, void* d_ws, size_t ws_size,
                              hipStream_t stream) {
    const float* boxes0  = (const float*)d_in[0];
    const float* scores0 = (const float*)d_in[1];
    const float* boxes1  = (const float*)d_in[2];
    const float* scores1 = (const float*)d_in[3];
    const float* boxes2  = (const float*)d_in[4];
    const float* scores2 = (const float*)d_in[5];
    const float* boxes3  = (const float*)d_in[6];
    const float* scores3 = (const float*)d_in[7];
    float* out = (float*)d_out;

    char* base = (char*)d_ws;
    float* ws_scores = (float*)base;                                      // 128000 B
    float* ws_boxes  = (float*)(base + 128000);                           // 512000 B
    unsigned long long* ws_mask = (unsigned long long*)(base + 640000);   // 4096000 B
    unsigned long long* ws_nz   = (unsigned long long*)(base + 4736000);  // 4096 B
    unsigned long long* cand    = (unsigned long long*)(base + 4740096);  // 524288 B
    unsigned* ghist             = (unsigned*)(base + 5264384);            // 1048576 B
    unsigned* counters          = (unsigned*)(base + 6312960);            // 128 B
    unsigned* thresh            = (unsigned*)(base + 6313088);            // 128 B

    // ---- try cooperative single launch (query co-residency per call) ----
    int blocksPerCU = 0;
    hipError_t qe = hipOccupancyMaxActiveBlocksPerMultiprocessor(
        &blocksPerCU, reinterpret_cast<const void*>(roi_coop_kernel), 512, 0);
    if (qe == hipSuccess && blocksPerCU >= 1) {
        void* args[] = {
            (void*)&boxes0, (void*)&scores0, (void*)&boxes1, (void*)&scores1,
            (void*)&boxes2, (void*)&scores2, (void*)&boxes3, (void*)&scores3,
            (void*)&ws_scores, (void*)&ws_boxes, (void*)&ws_mask, (void*)&ws_nz,
            (void*)&cand, (void*)&ghist, (void*)&counters, (void*)&thresh,
            (void*)&out };
        hipError_t le = hipLaunchCooperativeKernel(
            reinterpret_cast<const void*>(roi_coop_kernel),
            dim3(CGRID), dim3(512), args, 0, stream);
        if (le == hipSuccess) return;
        (void)hipGetLastError();   // clear; fall through to the verified chain
    }

    // ---- fallback: verified R16 chain ----
    init_kernel<<<128, 512, 0, stream>>>(ghist, ws_nz);
    hist_kernel<<<BATCH * NLVL * HB, 512, 0, stream>>>(
        scores0, scores1, scores2, scores3, ghist);
    select_kernel<<<BATCH * NLVL, 256, 0, stream>>>(ghist, thresh, counters);
    collect_kernel<<<BATCH * NLVL * HB, 512, 0, stream>>>(
        scores0, scores1, scores2, scores3, thresh, counters, cand);
    sortemit_kernel<<<BATCH * NLVL * SB, 256, 0, stream>>>(
        boxes0, boxes1, boxes2, boxes3, counters, cand, ws_scores, ws_boxes);
    mask_kernel<<<BATCH * NLVL * MBM, 256, 0, stream>>>(ws_boxes, ws_mask, ws_nz);
    greedy_kernel<<<BATCH * NLVL, 1024, 0, stream>>>(ws_scores, ws_boxes, ws_mask, ws_nz);
    final_merge_kernel<<<BATCH * NLVL, 1024, 0, stream>>>(ws_scores, ws_boxes, out);
}

// Round 22
// 95.839 us; speedup vs baseline: 1.0028x; 1.0028x over previous
//
#include <hip/hip_runtime.h>

#define PRE_K 1000
#define CAP   2048      // candidate buffer per level (>= PRE_K + max bin, pow2)
#define NBIN  8192      // 13-bit key-prefix histogram bins
#define NB    1000      // boxes per level after pre-NMS topk
#define NW    16        // 64-bit words covering NB bits
#define TOT   4000      // concatenated entries per batch
#define NLVL  4
#define BATCH 8
#define HB    8         // blocks per (b,lvl) for hist/collect
#define MBM   16        // blocks per (b,lvl) for mask build
#define SB    8         // blocks per (b,lvl) for sortemit (8*256 == CAP)

__device__ __forceinline__ unsigned f2key(float f) {
    unsigned u = __float_as_uint(f);
    return (u & 0x80000000u) ? ~u : (u | 0x80000000u);   // monotonic ascending
}
__device__ __forceinline__ float key2f(unsigned k) {
    unsigned u = (k & 0x80000000u) ? (k & 0x7FFFFFFFu) : ~k;
    return __uint_as_float(u);
}
__device__ __forceinline__ const float* lvl_scores(
    const float* s0, const float* s1, const float* s2, const float* s3, int lvl) {
    switch (lvl) { case 0: return s0; case 1: return s1; case 2: return s2; default: return s3; }
}
__device__ __forceinline__ const float* lvl_boxes(
    const float* b0, const float* b1, const float* b2, const float* b3, int lvl) {
    switch (lvl) { case 0: return b0; case 1: return b1; case 2: return b2; default: return b3; }
}
__device__ __forceinline__ int lvl_n(int lvl) {
    const int sizes[4] = {196608, 49152, 12288, 3072};
    return sizes[lvl];
}
__device__ __forceinline__ float bcast_f(float v, int i) {
    return __int_as_float(__builtin_amdgcn_readlane(__float_as_int(v), i));
}

// ---------------------------------------------------------------------------
// T0: zero global histograms + nonzero-row bitmaps (R10-verified)
// ---------------------------------------------------------------------------
__global__ __launch_bounds__(512) void init_kernel(
    unsigned* __restrict__ ghist, unsigned long long* __restrict__ ws_nz) {
    const int stride = gridDim.x * 512;
    for (int i = blockIdx.x * 512 + threadIdx.x; i < 32 * NBIN; i += stride)
        ghist[i] = 0u;
    for (int i = blockIdx.x * 512 + threadIdx.x; i < 32 * NW; i += stride)
        ws_nz[i] = 0ull;
}

// ---------------------------------------------------------------------------
// T1: per-(b,lvl) 13-bit-prefix histogram (R10-verified)
// ---------------------------------------------------------------------------
__global__ __launch_bounds__(512) void hist_kernel(
    const float* __restrict__ scores0, const float* __restrict__ scores1,
    const float* __restrict__ scores2, const float* __restrict__ scores3,
    unsigned* __restrict__ ghist)      // [32][NBIN]
{
    const int blk = blockIdx.x / HB;   // b*4 + lvl
    const int hb  = blockIdx.x % HB;
    const int b   = blk >> 2;
    const int lvl = blk & 3;
    const int n   = lvl_n(lvl);
    const float* sc = lvl_scores(scores0, scores1, scores2, scores3, lvl) + (size_t)b * n;

    __shared__ unsigned lhist[2][NBIN];   // 64 KB
    const int tid = threadIdx.x;
    const int rep = (tid >> 6) & 1;       // wave-uniform replica
    for (int i = tid; i < 2 * NBIN; i += 512) (&lhist[0][0])[i] = 0u;
    __syncthreads();

    const float4* sc4 = (const float4*)sc;
    const int n4 = n >> 2;                // all level sizes divisible by 4
    for (int i = hb * 512 + tid; i < n4; i += HB * 512) {
        float4 v = sc4[i];
        atomicAdd(&lhist[rep][f2key(v.x) >> 19], 1u);
        atomicAdd(&lhist[rep][f2key(v.y) >> 19], 1u);
        atomicAdd(&lhist[rep][f2key(v.z) >> 19], 1u);
        atomicAdd(&lhist[rep][f2key(v.w) >> 19], 1u);
    }
    __syncthreads();

    unsigned* gh = ghist + (size_t)blk * NBIN;
    for (int i = tid; i < NBIN; i += 512) {
        unsigned v = lhist[0][i] + lhist[1][i];
        if (v) atomicAdd(&gh[i], v);
    }
}

// ---------------------------------------------------------------------------
// T2: per-(b,lvl) threshold-bin selection (R10-verified); zero counters
// ---------------------------------------------------------------------------
__global__ __launch_bounds__(256) void select_kernel(
    const unsigned* __restrict__ ghist,   // [32][NBIN]
    unsigned* __restrict__ thresh,        // [32]
    unsigned* __restrict__ counters)      // [32]
{
    const int blk = blockIdx.x;
    const int tid = threadIdx.x;
    const unsigned* gh = ghist + (size_t)blk * NBIN;

    __shared__ unsigned csum[256];
    __shared__ int s_chunk;
    __shared__ unsigned s_before;

    unsigned s = 0;
    #pragma unroll 8
    for (int k = 0; k < 32; ++k) s += gh[tid * 32 + k];
    csum[tid] = s;
    __syncthreads();

    unsigned suf = 0;
    for (int c = tid + 1; c < 256; ++c) suf += csum[c];
    if (suf < PRE_K && suf + csum[tid] >= PRE_K) { s_chunk = tid; s_before = suf; }
    __syncthreads();

    if (tid == 0) {
        int C = s_chunk;
        unsigned acc = s_before;
        int T = C * 32;
        for (int bin = C * 32 + 31; bin >= C * 32; --bin) {
            acc += gh[bin];
            if (acc >= PRE_K) { T = bin; break; }
        }
        thresh[blk]   = (unsigned)T;
        counters[blk] = 0u;       // zero collect counter for this level
    }
}

// ---------------------------------------------------------------------------
// T3: collect candidates with key-bin >= threshold (R10-verified)
// ---------------------------------------------------------------------------
__global__ __launch_bounds__(512) void collect_kernel(
    const float* __restrict__ scores0, const float* __restrict__ scores1,
    const float* __restrict__ scores2, const float* __restrict__ scores3,
    const unsigned* __restrict__ thresh,
    unsigned* __restrict__ counters,
    unsigned long long* __restrict__ cand)   // [32][CAP]
{
    const int blk = blockIdx.x / HB;
    const int hb  = blockIdx.x % HB;
    const int b   = blk >> 2;
    const int lvl = blk & 3;
    const int n   = lvl_n(lvl);
    const float* sc = lvl_scores(scores0, scores1, scores2, scores3, lvl) + (size_t)b * n;
    const unsigned T = thresh[blk];
    unsigned long long* candp = cand + (size_t)blk * CAP;

    __shared__ unsigned long long cbuf[CAP];
    __shared__ unsigned ccnt, cbase;

    const int tid  = threadIdx.x;
    const int lane = tid & 63;
    if (tid == 0) ccnt = 0;
    __syncthreads();

    for (int i = hb * 512 + tid; i < n; i += HB * 512) {
        unsigned key = f2key(sc[i]);
        bool pred = (key >> 19) >= T;
        unsigned long long act = __ballot(pred);
        if (act) {
            int leader = __ffsll((long long)act) - 1;
            unsigned base = 0;
            if (lane == leader) base = atomicAdd(&ccnt, (unsigned)__popcll(act));
            base = __shfl(base, leader, 64);
            if (pred) {
                unsigned pos = base + (unsigned)__popcll(act & ((1ull << lane) - 1ull));
                if (pos < CAP)
                    cbuf[pos] = ((unsigned long long)key << 32) | (unsigned)(~i);
            }
        }
    }
    __syncthreads();
    unsigned cnt = ccnt; if (cnt > CAP) cnt = CAP;
    if (tid == 0) cbase = atomicAdd(&counters[blk], cnt);
    __syncthreads();
    const unsigned gb = cbase;
    for (unsigned i = tid; i < cnt; i += 512) {
        unsigned p = gb + i;
        if (p < CAP) candp[p] = cbuf[i];
    }
}

// ---------------------------------------------------------------------------
// T4: rank-by-count top-1000, WIDE + register-broadcast (R16-verified).
// ---------------------------------------------------------------------------
__global__ __launch_bounds__(256) void sortemit_kernel(
    const float* __restrict__ boxes0, const float* __restrict__ boxes1,
    const float* __restrict__ boxes2, const float* __restrict__ boxes3,
    const unsigned* __restrict__ counters,
    const unsigned long long* __restrict__ cand,
    float* __restrict__ ws_scores,   // [32][1000]
    float* __restrict__ ws_boxes)    // [32][1000][4]
{
    const int blk = blockIdx.x / SB;
    const int hb  = blockIdx.x % SB;
    const int b   = blk >> 2;
    const int lvl = blk & 3;
    const int n   = lvl_n(lvl);
    const float* bx = lvl_boxes(boxes0, boxes1, boxes2, boxes3, lvl) + (size_t)b * n * 4;
    const unsigned long long* candp = cand + (size_t)blk * CAP;

    __shared__ unsigned long long arr[CAP];      // 16 KB, zero-padded
    const int tid  = threadIdx.x;
    const int lane = tid & 63;
    int cnt = (int)counters[blk]; if (cnt > CAP) cnt = CAP;

    for (int i = tid; i < CAP; i += 256)
        arr[i] = (i < cnt) ? candp[i] : 0ull;
    __syncthreads();

    const int i = hb * 256 + tid;                // this thread's candidate
    const unsigned long long ci = (i < cnt) ? arr[i] : 0ull;
    int rank = 0;
    const int nch = (cnt + 63) >> 6;
    for (int c = 0; c < nch; ++c) {
        unsigned long long x = arr[c * 64 + lane];   // chunk -> lane regs
        unsigned xlo = (unsigned)x, xhi = (unsigned)(x >> 32);
        #pragma unroll
        for (int k = 0; k < 64; ++k) {
            unsigned long long xk =
                ((unsigned long long)(unsigned)__builtin_amdgcn_readlane((int)xhi, k) << 32) |
                (unsigned)__builtin_amdgcn_readlane((int)xlo, k);
            rank += (xk > ci);
        }
    }
    if (i < cnt && rank < PRE_K) {
        unsigned key = (unsigned)(ci >> 32);
        int idx = (int)(~(unsigned)ci);
        ws_scores[(size_t)blk * PRE_K + rank] = key2f(key);
        const float4 bb = ((const float4*)bx)[idx];
        float* dst = ws_boxes + ((size_t)blk * PRE_K + rank) * 4;
        dst[0] = bb.x; dst[1] = bb.y; dst[2] = bb.z; dst[3] = bb.w;
    }
}

// ---------------------------------------------------------------------------
// K4: mask build (R10-verified)
// ---------------------------------------------------------------------------
__global__ __launch_bounds__(256) void mask_kernel(
    const float* __restrict__ ws_boxes,
    unsigned long long* __restrict__ ws_mask,   // [32][1000][16]
    unsigned long long* __restrict__ ws_nz)     // [32][16]
{
    const int blk  = blockIdx.x / MBM;    // (b,lvl)
    const int mb   = blockIdx.x % MBM;
    const int tid  = threadIdx.x;
    const int lane = tid & 63;
    const int wv   = tid >> 6;            // wave 0..3

    __shared__ float4 sbox[1024];

    const float4* bxp = (const float4*)(ws_boxes + (size_t)blk * NB * 4);
    for (int i = tid; i < 1024; i += 256)
        sbox[i] = (i < NB) ? bxp[i] : make_float4(0.f, 0.f, 0.f, 0.f);
    __syncthreads();

    unsigned long long* maskp = ws_mask + (size_t)blk * NB * NW;
    unsigned long long* nzp   = ws_nz + (size_t)blk * NW;
    const double CSUM = (double)__uint_as_float(0x3F333333u)
                      + (double)__uint_as_float(0x3F333334u);   // exact 2*midpoint

    for (int t = mb * 4 + wv; t < 136; t += MBM * 4) {
        // decode t -> (w, rb): word w has row-blocks 0..w
        int w = 0, acc = 0;
        while (acc + w + 1 <= t) { acc += w + 1; ++w; }
        const int rb = t - acc;
        const int rbase = rb * 64;

        const float4 rbx = sbox[rbase + lane];     // lane's ROW box
        const float   ra = (rbx.z - rbx.x) * (rbx.w - rbx.y);
        const float4 cbx = sbox[w * 64 + lane];    // lane's slot of COL boxes
        const float   ca = (cbx.z - cbx.x) * (cbx.w - cbx.y);

        unsigned long long myw = 0ull;
        #pragma unroll
        for (int jj = 0; jj < 64; ++jj) {
            const float cy1 = bcast_f(cbx.x, jj);
            const float cx1 = bcast_f(cbx.y, jj);
            const float cy2 = bcast_f(cbx.z, jj);
            const float cx2 = bcast_f(cbx.w, jj);
            const float caj = bcast_f(ca, jj);
            float iy1 = fmaxf(rbx.x, cy1);
            float ix1 = fmaxf(rbx.y, cx1);
            float iy2 = fminf(rbx.z, cy2);
            float ix2 = fminf(rbx.w, cx2);
            float ih = fmaxf(iy2 - iy1, 0.0f);
            float iw = fmaxf(ix2 - ix1, 0.0f);
            float inter = ih * iw;
            float uni = ra + caj - inter;
            bool pred = (uni > 0.0f) &&
                        (2.0 * (double)inter >= CSUM * (double)uni);
            myw |= ((unsigned long long)pred) << jj;
        }
        if (w == rb)
            myw &= ~((2ull << lane) - 1ull);       // keep only jj > lane (lane63 -> 0)
        if (rbase + lane < NB)
            maskp[(size_t)(rbase + lane) * NW + w] = myw;
        // nonzero-row bitmap for chunk rb
        unsigned long long nzb = __ballot(myw != 0ull);
        if (lane == 0 && nzb) atomicOr(&nzp[rb], nzb);
    }
}

// ---------------------------------------------------------------------------
// K5: sparse greedy NMS (R10-verified)
// ---------------------------------------------------------------------------
__global__ __launch_bounds__(1024) void greedy_kernel(
    float* __restrict__ ws_scores,   // [32][1000] in-place
    float* __restrict__ ws_boxes,    // [32][1000][4] in-place
    const unsigned long long* __restrict__ ws_mask,
    const unsigned long long* __restrict__ ws_nz)
{
    const int blk  = blockIdx.x;
    const int tid  = threadIdx.x;
    const int lane = tid & 63;
    const int wv   = tid >> 6;       // 0..15

    __shared__ unsigned long long Mrow[NB * NW];     // 128000 B (worst case)
    __shared__ float4 sbox[NB];                      // 16000 B
    __shared__ float  ssc[NB];                       //  4000 B
    __shared__ unsigned long long nzlds[NW];
    __shared__ unsigned long long keepw[NW];
    __shared__ int wprefix[NW];
    __shared__ int slist[NB];                        // 4000 B
    __shared__ int sL;

    float* scp = ws_scores + (size_t)blk * NB;
    float* bxp = ws_boxes  + (size_t)blk * NB * 4;
    const unsigned long long* mrows = ws_mask + (size_t)blk * NB * NW;

    if (tid < NW) nzlds[tid] = ws_nz[(size_t)blk * NW + tid];
    for (int i = tid; i < NB; i += 1024) {
        sbox[i] = ((const float4*)bxp)[i];
        ssc[i]  = scp[i];
    }
    // initial keep bits: wave wv computes word wv
    {
        const int j = wv * 64 + lane;
        bool pred = (j < NB) && (scp[j] > 0.0f);
        unsigned long long bal = __ballot(pred);
        if (lane == 0) keepw[wv] = bal;
    }
    __syncthreads();

    // ---- ordered candidate (suppressor) row list ----
    if (tid == 0) {
        int L = 0;
        for (int c = 0; c < NW; ++c) {
            unsigned long long p = nzlds[c];
            while (p) {
                int i = __ffsll((long long)p) - 1;
                slist[L++] = c * 64 + i;
                p &= p - 1;
            }
        }
        sL = L;
    }
    __syncthreads();
    const int L = sL;

    // ---- stage candidate rows' mask words (sparse gather) ----
    for (int idx = tid; idx < L * NW; idx += 1024) {
        int r = slist[idx >> 4];
        Mrow[idx] = mrows[(size_t)r * NW + (idx & 15)];
    }
    __syncthreads();

    // ---- serial pass on wave 0, 1-deep prefetch ----
    if (tid < 64) {
        unsigned long long kp = (lane < NW) ? keepw[lane] : 0ull;
        unsigned long long mnext = (L > 0 && lane < NW) ? Mrow[lane] : 0ull;
        int rnext = (L > 0) ? slist[0] : 0;
        for (int k = 0; k < L; ++k) {
            unsigned long long m = mnext;
            const int r = rnext;
            if (k + 1 < L) {
                rnext = slist[k + 1];
                mnext = (lane < NW) ? Mrow[(size_t)(k + 1) * NW + lane] : 0ull;
            }
            const int c = r >> 6;
            unsigned klo = (unsigned)__builtin_amdgcn_readlane((int)(unsigned)kp, c);
            unsigned khi = (unsigned)__builtin_amdgcn_readlane((int)(unsigned)(kp >> 32), c);
            unsigned long long kw = ((unsigned long long)khi << 32) | klo;
            if ((kw >> (r & 63)) & 1ull) {           // row still kept -> applies
                unsigned long long mm = (lane >= c) ? m : 0ull;   // mask garbage words
                kp &= ~mm;
            }
        }
        if (lane < NW) keepw[lane] = kp;
    }
    __syncthreads();
    if (tid == 0) {
        int acc = 0;
        for (int w = 0; w < NW; ++w) { wprefix[w] = acc; acc += __popcll(keepw[w]); }
    }
    __syncthreads();

    // ---- zero-fill then stable scatter of survivors (from LDS copies) ----
    for (int i = tid; i < NB; i += 1024) scp[i] = 0.0f;
    for (int i = tid; i < NB * 4; i += 1024) bxp[i] = 0.0f;
    __syncthreads();
    for (int i = tid; i < NB; i += 1024) {
        const int w = i >> 6;
        const unsigned long long kw = keepw[w];
        if ((kw >> (i & 63)) & 1ull) {
            int rank = wprefix[w] + __popcll(kw & ((1ull << (i & 63)) - 1ull));
            scp[rank] = ssc[i];
            float4 bb = sbox[i];
            float* dst = bxp + (size_t)rank * 4;
            dst[0] = bb.x; dst[1] = bb.y; dst[2] = bb.z; dst[3] = bb.w;
        }
    }
}

// ---------------------------------------------------------------------------
// K6: final top-1000 by 4-way merge-rank (R7-verified).
// ---------------------------------------------------------------------------
__global__ __launch_bounds__(1024) void final_merge_kernel(
    const float* __restrict__ ws_scores,  // [8][4][1000]
    const float* __restrict__ ws_boxes,   // [8][4000][4]
    float* __restrict__ out)              // rois (8*1000*4) then scores (8*1000)
{
    const int blk = blockIdx.x;          // b*4 + lvl
    const int b   = blk >> 2;
    const int lvl = blk & 3;
    const int tid = threadIdx.x;

    __shared__ unsigned long long lists[NLVL][PRE_K];   // 32000 B

    for (int i = tid; i < TOT; i += 1024) {
        unsigned u = f2key(ws_scores[(size_t)b * TOT + i]);
        lists[i / PRE_K][i % PRE_K] =
            ((unsigned long long)u << 32) | (unsigned)(~i);
    }
    __syncthreads();

    float* out_rois   = out;            // (8,1000,4)
    float* out_scores = out + 32000;    // (8,1000)

    for (int r = tid; r < PRE_K; r += 1024) {
        const unsigned long long c = lists[lvl][r];
        int rank = r;
        #pragma unroll
        for (int l = 0; l < NLVL; ++l) {
            if (l == lvl) continue;
            int lo = 0, hi = PRE_K;
            while (lo < hi) {
                int mid = (lo + hi) >> 1;
                if (lists[l][mid] > c) lo = mid + 1; else hi = mid;
            }
            rank += lo;
        }
        if (rank < PRE_K) {
            out_scores[(size_t)b * PRE_K + rank] = key2f((unsigned)(c >> 32));
            const int pos = lvl * PRE_K + r;     // == ~(unsigned)c
            const float4 bb = ((const float4*)ws_boxes)[(size_t)b * TOT + pos];
            float* dst = out_rois + ((size_t)b * PRE_K + rank) * 4;
            dst[0] = bb.x; dst[1] = bb.y; dst[2] = bb.z; dst[3] = bb.w;
        }
    }
}

// ---------------------------------------------------------------------------
extern "C" void kernel_launch(void* const* d_in, const int* in_sizes, int n_in,
                              void* d_out, int out_size, void* d_ws, size_t ws_size,
                              hipStream_t stream) {
    // setup_inputs() dict order: boxes_p2, scores_p2, boxes_p3, scores_p3,
    //                            boxes_p4, scores_p4, boxes_p5, scores_p5
    const float* boxes0  = (const float*)d_in[0];
    const float* scores0 = (const float*)d_in[1];
    const float* boxes1  = (const float*)d_in[2];
    const float* scores1 = (const float*)d_in[3];
    const float* boxes2  = (const float*)d_in[4];
    const float* scores2 = (const float*)d_in[5];
    const float* boxes3  = (const float*)d_in[6];
    const float* scores3 = (const float*)d_in[7];
    float* out = (float*)d_out;

    // ws carve (disjoint; R10 layout):
    char* base = (char*)d_ws;
    float* ws_scores = (float*)base;                                      // 128000 B
    float* ws_boxes  = (float*)(base + 128000);                           // 512000 B
    unsigned long long* ws_mask = (unsigned long long*)(base + 640000);   // 4096000 B
    unsigned long long* ws_nz   = (unsigned long long*)(base + 4736000);  // 4096 B
    unsigned long long* cand    = (unsigned long long*)(base + 4740096);  // 524288 B
    unsigned* ghist             = (unsigned*)(base + 5264384);            // 1048576 B
    unsigned* counters          = (unsigned*)(base + 6312960);            // 128 B
    unsigned* thresh            = (unsigned*)(base + 6313088);            // 128 B

    init_kernel<<<128, 512, 0, stream>>>(ghist, ws_nz);
    hist_kernel<<<BATCH * NLVL * HB, 512, 0, stream>>>(
        scores0, scores1, scores2, scores3, ghist);
    select_kernel<<<BATCH * NLVL, 256, 0, stream>>>(ghist, thresh, counters);
    collect_kernel<<<BATCH * NLVL * HB, 512, 0, stream>>>(
        scores0, scores1, scores2, scores3, thresh, counters, cand);
    sortemit_kernel<<<BATCH * NLVL * SB, 256, 0, stream>>>(
        boxes0, boxes1, boxes2, boxes3, counters, cand, ws_scores, ws_boxes);
    mask_kernel<<<BATCH * NLVL * MBM, 256, 0, stream>>>(ws_boxes, ws_mask, ws_nz);
    greedy_kernel<<<BATCH * NLVL, 1024, 0, stream>>>(ws_scores, ws_boxes, ws_mask, ws_nz);
    final_merge_kernel<<<BATCH * NLVL, 1024, 0, stream>>>(ws_scores, ws_boxes, out);
}